// Round 9
// baseline (502.958 us; speedup 1.0000x reference)
//
#include <hip/hip_runtime.h>
#include <hip/hip_cooperative_groups.h>
#include <math.h>

#define NCLS    16
#define B_ROWS  65536
#define MARGINc 1.0f
#define NWIN    1024       // virtual windows: 16 classes x 64 windows x 128 rows

namespace cg = cooperative_groups;

#define CADD(V) { acc.x += V.x; acc.y += V.y; acc.z += V.z; acc.w += V.w; }
#define DSQ(V, C) { float dx = V.x - C.x, dy = V.y - C.y, dz = V.z - C.z, dw = V.w - C.w; \
                    accT += dx * dx + dy * dy + dz * dz + dw * dw; }

// ======================= mega-kernel ws layout (float offsets) ==============
#define M_CE     0
#define M_CNT    32        // 16 int
#define M_OFFS   48        // 16 int
#define M_INV    64        // 16 f32
#define M_CEPART 256       // 1024 f32
#define M_HIST   2048      // 16*1024 int
#define M_BASES  32768     // 16*1024 int
#define M_CENT   65536     // 16384 f32
#define M_ORDER  81920     // 65536 int
#define M_DISTP  147456    // 1024 f32
#define M_PART   163840    // 1024*1024 f32 (4 MB)

// Grid-size-agnostic cooperative mega-kernel: all phases stride over NWIN
// virtual windows, so any co-resident grid size NB works.
__global__ __launch_bounds__(256) void k_mega(const float* __restrict__ logits,
                                              const int* __restrict__ labels,
                                              const float* __restrict__ feat,
                                              float* __restrict__ ws,
                                              float* __restrict__ out) {
    cg::grid_group gridg = cg::this_grid();
    __shared__ int ish[NCLS];
    __shared__ float fsh[4];
    __shared__ float red[256];
    __shared__ int ctot[NCLS];

    const int tid = threadIdx.x, lane = tid & 63, w = tid >> 6;
    const int b0 = blockIdx.x;
    const int NB = gridDim.x;
    int* wsi = (int*)ws;
    const float4* f4 = (const float4*)feat;

    //// P0: CE + per-window class histogram (64 rows/window; 4 lanes per row)
    for (int vb = b0; vb < NWIN; vb += NB) {
        if (tid < NCLS) ish[tid] = 0;
        __syncthreads();
        int q = tid >> 2, sub = tid & 3;
        int row = vb * 64 + q;
        float4 lg = ((const float4*)(logits + (size_t)row * 16))[sub];
        int lab = labels[row];
        float m = fmaxf(fmaxf(lg.x, lg.y), fmaxf(lg.z, lg.w));
        m = fmaxf(m, __shfl_xor(m, 1, 64));
        m = fmaxf(m, __shfl_xor(m, 2, 64));
        float s = expf(lg.x - m) + expf(lg.y - m) + expf(lg.z - m) + expf(lg.w - m);
        s += __shfl_xor(s, 1, 64);
        s += __shfl_xor(s, 2, 64);
        float pick = 0.f;
        if ((lab >> 2) == sub) {
            int cmp = lab & 3;
            pick = cmp == 0 ? lg.x : cmp == 1 ? lg.y : cmp == 2 ? lg.z : lg.w;
        }
        pick += __shfl_xor(pick, 1, 64);
        pick += __shfl_xor(pick, 2, 64);
        float ce = 0.f;
        if (sub == 0) {
            ce = m + logf(s) - pick;
            atomicAdd(&ish[lab], 1);           // LDS atomic, intra-block
        }
        for (int o = 32; o >= 1; o >>= 1) ce += __shfl_down(ce, o, 64);
        if (lane == 0) fsh[w] = ce;
        __syncthreads();
        if (tid == 0) ws[M_CEPART + vb] = fsh[0] + fsh[1] + fsh[2] + fsh[3];
        if (tid < NCLS) wsi[M_HIST + tid * 1024 + vb] = ish[tid];
        __syncthreads();
    }
    gridg.sync();

    //// P1: per-class exclusive scan over the 1024 windows (block 0 only)
    if (b0 == 0) {
        for (int ci = 0; ci < 4; ++ci) {
            int c = w * 4 + ci;
            int carry = 0;
            for (int s = 0; s < 16; ++s) {
                int v = wsi[M_HIST + c * 1024 + s * 64 + lane];
                int x = v;
                for (int o = 1; o < 64; o <<= 1) {
                    int y = __shfl_up(x, o, 64);
                    if (lane >= o) x += y;
                }
                wsi[M_BASES + c * 1024 + s * 64 + lane] = carry + x - v;
                carry += __shfl(x, 63, 64);
            }
            if (lane == 0) ctot[c] = carry;
        }
        __syncthreads();
        if (tid == 0) {
            int off = 0;
            for (int c = 0; c < NCLS; ++c) {
                int cnt = ctot[c];
                wsi[M_CNT + c] = cnt;
                wsi[M_OFFS + c] = off;
                ws[M_INV + c] = 1.0f / (float)(cnt > 0 ? cnt : 1);
                off += cnt;
            }
        }
        float sv = ws[M_CEPART + tid] + ws[M_CEPART + tid + 256]
                 + ws[M_CEPART + tid + 512] + ws[M_CEPART + tid + 768];
        for (int o = 32; o >= 1; o >>= 1) sv += __shfl_down(sv, o, 64);
        if (lane == 0) fsh[w] = sv;
        __syncthreads();
        if (tid == 0) ws[M_CE] = fsh[0] + fsh[1] + fsh[2] + fsh[3];
    }
    gridg.sync();

    //// P2: counting-sort scatter (LDS cursors seeded from bases)
    for (int vb = b0; vb < NWIN; vb += NB) {
        if (tid < NCLS) ish[tid] = wsi[M_OFFS + tid] + wsi[M_BASES + tid * 1024 + vb];
        __syncthreads();
        if (tid < 64) {
            int row = vb * 64 + tid;
            int lab = labels[row];
            int pos = atomicAdd(&ish[lab], 1);
            wsi[M_ORDER + pos] = row;
        }
        __syncthreads();
    }
    gridg.sync();

    //// P3: class sums — window = 128 rows of ONE class, register accumulate
    for (int vb = b0; vb < NWIN; vb += NB) {
        int c = vb >> 6, q = vb & 63;
        int cnt = wsi[M_CNT + c];
        int s0 = q * 128;
        int n = cnt - s0; n = n < 0 ? 0 : (n > 128 ? 128 : n);
        const int* ord = wsi + M_ORDER + wsi[M_OFFS + c] + s0;
        float4 acc = make_float4(0.f, 0.f, 0.f, 0.f);
        int i = 0;
        for (; i + 8 <= n; i += 8) {
            int i0 = ord[i], i1 = ord[i + 1], i2 = ord[i + 2], i3 = ord[i + 3];
            int i4 = ord[i + 4], i5 = ord[i + 5], i6 = ord[i + 6], i7 = ord[i + 7];
            float4 v0 = f4[(size_t)i0 * 256 + tid];
            float4 v1 = f4[(size_t)i1 * 256 + tid];
            float4 v2 = f4[(size_t)i2 * 256 + tid];
            float4 v3 = f4[(size_t)i3 * 256 + tid];
            float4 v4 = f4[(size_t)i4 * 256 + tid];
            float4 v5 = f4[(size_t)i5 * 256 + tid];
            float4 v6 = f4[(size_t)i6 * 256 + tid];
            float4 v7 = f4[(size_t)i7 * 256 + tid];
            CADD(v0) CADD(v1) CADD(v2) CADD(v3)
            CADD(v4) CADD(v5) CADD(v6) CADD(v7)
        }
        for (; i < n; ++i) {
            float4 v = f4[(size_t)ord[i] * 256 + tid];
            CADD(v)
        }
        ((float4*)(ws + M_PART))[vb * 256 + tid] = acc;   // plain store
    }
    gridg.sync();

    //// P4: centroids (virtual blocks 0..63; empty windows stored zeros)
    for (int vb = b0; vb < 64; vb += NB) {
        int j = vb * 256 + tid;                // 0..16383
        int c = j >> 10, d = j & 1023;
        float s = 0.f;
#pragma unroll 8
        for (int q = 0; q < 64; ++q) s += ws[M_PART + (size_t)(c * 64 + q) * 1024 + d];
        ws[M_CENT + j] = s * ws[M_INV + c];
    }
    gridg.sync();

    //// P5: distances — same windows as P3, walked in REVERSE (L3/L2 reuse);
    //// class is window-uniform -> centroid in 4 registers/lane
    {
        const float4* c4 = (const float4*)(ws + M_CENT);
        int kit = (NWIN - 1 - b0) / NB;
        for (int k = kit; k >= 0; --k) {
            int vb = b0 + k * NB;
            int c = vb >> 6, q = vb & 63;
            int cnt = wsi[M_CNT + c];
            int s0 = q * 128;
            int n = cnt - s0; n = n < 0 ? 0 : (n > 128 ? 128 : n);
            const int* ord = wsi + M_ORDER + wsi[M_OFFS + c] + s0;
            float4 c0 = c4[c * 256 + 0 * 64 + lane];
            float4 c1 = c4[c * 256 + 1 * 64 + lane];
            float4 c2 = c4[c * 256 + 2 * 64 + lane];
            float4 c3 = c4[c * 256 + 3 * 64 + lane];
            float wsum = 0.f;
            int rbeg = w * 32;
            int rend = rbeg + 32; if (rend > n) rend = n;
            int i = rend - 1;
            for (; i >= rbeg + 1; i -= 2) {
                int ra = ord[i], rb = ord[i - 1];
                float4 va0 = f4[(size_t)ra * 256 + 0 * 64 + lane];
                float4 va1 = f4[(size_t)ra * 256 + 1 * 64 + lane];
                float4 va2 = f4[(size_t)ra * 256 + 2 * 64 + lane];
                float4 va3 = f4[(size_t)ra * 256 + 3 * 64 + lane];
                float4 vb0 = f4[(size_t)rb * 256 + 0 * 64 + lane];
                float4 vb1 = f4[(size_t)rb * 256 + 1 * 64 + lane];
                float4 vb2 = f4[(size_t)rb * 256 + 2 * 64 + lane];
                float4 vb3 = f4[(size_t)rb * 256 + 3 * 64 + lane];
                float accT;
                accT = 0.f; DSQ(va0, c0) DSQ(va1, c1) DSQ(va2, c2) DSQ(va3, c3)
                float accA = accT;
                accT = 0.f; DSQ(vb0, c0) DSQ(vb1, c1) DSQ(vb2, c2) DSQ(vb3, c3)
                float accB = accT;
                for (int o = 32; o >= 1; o >>= 1) {
                    accA += __shfl_down(accA, o, 64);
                    accB += __shfl_down(accB, o, 64);
                }
                if (lane == 0) wsum += sqrtf(accA) + sqrtf(accB);
            }
            if (i == rbeg) {
                int ra = ord[i];
                float4 va0 = f4[(size_t)ra * 256 + 0 * 64 + lane];
                float4 va1 = f4[(size_t)ra * 256 + 1 * 64 + lane];
                float4 va2 = f4[(size_t)ra * 256 + 2 * 64 + lane];
                float4 va3 = f4[(size_t)ra * 256 + 3 * 64 + lane];
                float accT = 0.f;
                DSQ(va0, c0) DSQ(va1, c1) DSQ(va2, c2) DSQ(va3, c3)
                for (int o = 32; o >= 1; o >>= 1) accT += __shfl_down(accT, o, 64);
                if (lane == 0) wsum += sqrtf(accT);
            }
            if (lane == 0) fsh[w] = wsum;
            __syncthreads();
            if (tid == 0) ws[M_DISTP + vb] = fsh[0] + fsh[1] + fsh[2] + fsh[3];
            __syncthreads();
        }
    }
    gridg.sync();

    //// P6: final combine (block 0)
    if (b0 == 0) {
        const int* cnts = wsi + M_CNT;
        int c = tid >> 4, g = tid & 15;
        float s = ws[M_DISTP + c * 64 + g]      + ws[M_DISTP + c * 64 + g + 16]
                + ws[M_DISTP + c * 64 + g + 32] + ws[M_DISTP + c * 64 + g + 48];
        red[tid] = s;                          // red[c*16+g]
        __syncthreads();

        const float4* c4 = (const float4*)(ws + M_CENT);
        float interAcc = 0.f; int pairAcc = 0;
        for (int p = w; p < 120; p += 4) {
            int i = 0, rem = p;
            while (rem >= 15 - i) { rem -= 15 - i; ++i; }
            int j = i + 1 + rem;
            int ci = cnts[i], cj = cnts[j];
            float acc = 0.f;
#pragma unroll
            for (int k = 0; k < 4; ++k) {
                float4 a = c4[i * 256 + k * 64 + lane];
                float4 bb = c4[j * 256 + k * 64 + lane];
                float dx = a.x - bb.x, dy = a.y - bb.y, dz = a.z - bb.z, dw = a.w - bb.w;
                acc += dx * dx + dy * dy + dz * dz + dw * dw;
            }
            for (int o = 32; o >= 1; o >>= 1) acc += __shfl_down(acc, o, 64);
            if (lane == 0 && ci > 0 && cj > 0) {
                float t = MARGINc - sqrtf(acc);
                if (t > 0.f) interAcc += t;
                pairAcc += 1;
            }
        }
        if (lane == 0) { fsh[w] = interAcc; ish[w] = pairAcc; }
        __syncthreads();
        if (tid == 0) {
            float interSum = fsh[0] + fsh[1] + fsh[2] + fsh[3];
            int np = ish[0] + ish[1] + ish[2] + ish[3];
            float inter = np > 0 ? interSum / (float)np : 0.f;
            float intra = 0.f; int nv = 0;
            for (int cc = 0; cc < NCLS; ++cc) {
                float dsum = 0.f;
                for (int gg = 0; gg < 16; ++gg) dsum += red[cc * 16 + gg];
                if (cnts[cc] > 0) { intra += dsum * ws[M_INV + cc]; nv++; }
            }
            intra = nv > 0 ? intra / (float)nv : 0.f;
            float ce = ws[M_CE] / (float)B_ROWS;
            out[0] = ce + inter + intra;
        }
    }
}

// ======================= fallback: proven R7 pipeline =======================
#define CHUNK     32
#define VCPC      256
#define KMAXPC    256
#define NBLK_CS   2048
#define NBLK_DIST 2048

#define F_CE     0
#define F_CNT    32
#define F_OFFS   48
#define F_INV    64
#define F_CEPART 256
#define F_HIST   1024
#define F_BASES  8192
#define F_CENT   16384
#define F_ORDER  32768
#define F_DISTP  98304
#define F_PART   131072

__global__ __launch_bounds__(256) void k7_ce_hist(const float* __restrict__ logits,
                                                  const int* __restrict__ labels,
                                                  float* __restrict__ ws) {
    __shared__ int hist[NCLS];
    __shared__ float cew[4];
    int tid = threadIdx.x, lane = tid & 63, w = tid >> 6;
    int b = blockIdx.x;
    if (tid < NCLS) hist[tid] = 0;
    __syncthreads();
    int row = b * 256 + tid;
    const float4* lg = (const float4*)(logits + (size_t)row * 16);
    float4 a = lg[0], b4 = lg[1], c = lg[2], d = lg[3];
    float m = fmaxf(fmaxf(fmaxf(a.x, a.y), fmaxf(a.z, a.w)),
                    fmaxf(fmaxf(b4.x, b4.y), fmaxf(b4.z, b4.w)));
    m = fmaxf(m, fmaxf(fmaxf(c.x, c.y), fmaxf(c.z, c.w)));
    m = fmaxf(m, fmaxf(fmaxf(d.x, d.y), fmaxf(d.z, d.w)));
    float s = expf(a.x - m) + expf(a.y - m) + expf(a.z - m) + expf(a.w - m)
            + expf(b4.x - m) + expf(b4.y - m) + expf(b4.z - m) + expf(b4.w - m)
            + expf(c.x - m) + expf(c.y - m) + expf(c.z - m) + expf(c.w - m)
            + expf(d.x - m) + expf(d.y - m) + expf(d.z - m) + expf(d.w - m);
    int lab = labels[row];
    atomicAdd(&hist[lab], 1);
    float xl = logits[(size_t)row * 16 + lab];
    float ce = (m + logf(s)) - xl;
    for (int o = 32; o >= 1; o >>= 1) ce += __shfl_down(ce, o, 64);
    if (lane == 0) cew[w] = ce;
    __syncthreads();
    if (tid == 0) ws[F_CEPART + b] = cew[0] + cew[1] + cew[2] + cew[3];
    if (tid < NCLS) ((int*)ws)[F_HIST + tid * 256 + b] = hist[tid];
}

__global__ __launch_bounds__(1024) void k7_prefix(float* __restrict__ ws) {
    __shared__ int ctot[NCLS];
    __shared__ float cew[4];
    int tid = threadIdx.x, lane = tid & 63, w = tid >> 6;
    const int* hist = (const int*)ws + F_HIST;
    int* bases = (int*)ws + F_BASES;
    int base = lane * 4;
    int v0 = hist[w * 256 + base + 0];
    int v1 = hist[w * 256 + base + 1];
    int v2 = hist[w * 256 + base + 2];
    int v3 = hist[w * 256 + base + 3];
    int tot = v0 + v1 + v2 + v3;
    int x = tot;
    for (int o = 1; o < 64; o <<= 1) {
        int y = __shfl_up(x, o, 64);
        if (lane >= o) x += y;
    }
    int excl = x - tot;
    if (lane == 63) ctot[w] = x;
    __syncthreads();
    int off = 0;
    for (int cc = 0; cc < NCLS; ++cc) if (cc < w) off += ctot[cc];
    bases[w * 256 + base + 0] = off + excl;
    bases[w * 256 + base + 1] = off + excl + v0;
    bases[w * 256 + base + 2] = off + excl + v0 + v1;
    bases[w * 256 + base + 3] = off + excl + v0 + v1 + v2;
    if (lane == 0) {
        int cnt = ctot[w];
        ((int*)ws)[F_CNT + w] = cnt;
        ((int*)ws)[F_OFFS + w] = off;
        ws[F_INV + w] = 1.0f / (float)(cnt > 0 ? cnt : 1);
    }
    float s = (tid < 256) ? ws[F_CEPART + tid] : 0.f;
    if (tid < 256) {
        for (int o = 32; o >= 1; o >>= 1) s += __shfl_down(s, o, 64);
        if (lane == 0) cew[w] = s;
    }
    __syncthreads();
    if (tid == 0) ws[F_CE] = cew[0] + cew[1] + cew[2] + cew[3];
}

__global__ __launch_bounds__(256) void k7_scatter(const int* __restrict__ labels,
                                                  float* __restrict__ ws) {
    __shared__ int cur[NCLS];
    int tid = threadIdx.x, b = blockIdx.x;
    if (tid < NCLS) cur[tid] = ((int*)ws)[F_BASES + tid * 256 + b];
    __syncthreads();
    int row = b * 256 + tid;
    int lab = labels[row];
    int pos = atomicAdd(&cur[lab], 1);
    ((int*)ws)[F_ORDER + pos] = row;
}

__global__ __launch_bounds__(256) void k7_csums(const float* __restrict__ feat,
                                                float* __restrict__ ws) {
    int tid = threadIdx.x;
    const int* cnts  = (const int*)ws + F_CNT;
    const int* offs  = (const int*)ws + F_OFFS;
    const int* order = (const int*)ws + F_ORDER;
    const float4* f4 = (const float4*)feat;
    float4* part4 = (float4*)(ws + F_PART);
    for (int vc = blockIdx.x; vc < NCLS * VCPC; vc += NBLK_CS) {
        int c = vc >> 8, k = vc & (VCPC - 1);
        int cnt = cnts[c];
        int s0 = k * CHUNK;
        if (s0 >= cnt) continue;
        int e = s0 + CHUNK; if (e > cnt) e = cnt;
        const int* ord = order + offs[c] + s0;
        int n = e - s0;
        float4 acc = make_float4(0.f, 0.f, 0.f, 0.f);
        int i = 0;
        for (; i + 8 <= n; i += 8) {
            int i0 = ord[i], i1 = ord[i + 1], i2 = ord[i + 2], i3 = ord[i + 3];
            int i4 = ord[i + 4], i5 = ord[i + 5], i6 = ord[i + 6], i7 = ord[i + 7];
            float4 v0 = f4[(size_t)i0 * 256 + tid];
            float4 v1 = f4[(size_t)i1 * 256 + tid];
            float4 v2 = f4[(size_t)i2 * 256 + tid];
            float4 v3 = f4[(size_t)i3 * 256 + tid];
            float4 v4 = f4[(size_t)i4 * 256 + tid];
            float4 v5 = f4[(size_t)i5 * 256 + tid];
            float4 v6 = f4[(size_t)i6 * 256 + tid];
            float4 v7 = f4[(size_t)i7 * 256 + tid];
            CADD(v0) CADD(v1) CADD(v2) CADD(v3)
            CADD(v4) CADD(v5) CADD(v6) CADD(v7)
        }
        for (; i < n; ++i) {
            float4 v = f4[(size_t)ord[i] * 256 + tid];
            CADD(v)
        }
        part4[(size_t)vc * 256 + tid] = acc;
    }
}

__global__ __launch_bounds__(256) void k7_cent(float* __restrict__ ws) {
    int j = blockIdx.x * 256 + threadIdx.x;
    int c = j >> 10, d = j & 1023;
    int cnt = ((const int*)ws)[F_CNT + c];
    int kmax = (cnt + CHUNK - 1) >> 5;
    const float* part = ws + F_PART + (size_t)c * KMAXPC * 1024 + d;
    float s = 0.f;
    int k = 0;
    for (; k + 4 <= kmax; k += 4)
        s += part[(size_t)k * 1024] + part[(size_t)(k + 1) * 1024]
           + part[(size_t)(k + 2) * 1024] + part[(size_t)(k + 3) * 1024];
    for (; k < kmax; ++k) s += part[(size_t)k * 1024];
    ws[F_CENT + j] = s * ws[F_INV + c];
}

__global__ __launch_bounds__(256) void k7_dist(const float* __restrict__ feat,
                                               float* __restrict__ ws) {
    __shared__ float red[4];
    int tid = threadIdx.x, lane = tid & 63, w = tid >> 6;
    const int* cnts  = (const int*)ws + F_CNT;
    const int* offs  = (const int*)ws + F_OFFS;
    const int* order = (const int*)ws + F_ORDER;
    const float4* f4 = (const float4*)feat;
    const float4* c4 = (const float4*)(ws + F_CENT);
    float* distp = ws + F_DISTP;
    for (int it = 0; it < (NCLS * VCPC) / NBLK_DIST; ++it) {
        int vc = (NCLS * VCPC - 1) - (blockIdx.x + it * NBLK_DIST);
        int c = vc >> 8, k = vc & (VCPC - 1);
        int cnt = cnts[c];
        int s0 = k * CHUNK;
        if (s0 >= cnt) { if (tid == 0) distp[vc] = 0.f; continue; }
        int n = cnt - s0; if (n > CHUNK) n = CHUNK;
        const int* ord = order + offs[c] + s0;
        float4 c0 = c4[c * 256 + 0 * 64 + lane];
        float4 c1 = c4[c * 256 + 1 * 64 + lane];
        float4 c2 = c4[c * 256 + 2 * 64 + lane];
        float4 c3 = c4[c * 256 + 3 * 64 + lane];
        float wsum = 0.f;
        int rbeg = w * 8;
        int rend = rbeg + 8; if (rend > n) rend = n;
        int i = rbeg;
        for (; i + 2 <= rend; i += 2) {
            int ra = ord[i], rb = ord[i + 1];
            float4 va0 = f4[(size_t)ra * 256 + 0 * 64 + lane];
            float4 va1 = f4[(size_t)ra * 256 + 1 * 64 + lane];
            float4 va2 = f4[(size_t)ra * 256 + 2 * 64 + lane];
            float4 va3 = f4[(size_t)ra * 256 + 3 * 64 + lane];
            float4 vb0 = f4[(size_t)rb * 256 + 0 * 64 + lane];
            float4 vb1 = f4[(size_t)rb * 256 + 1 * 64 + lane];
            float4 vb2 = f4[(size_t)rb * 256 + 2 * 64 + lane];
            float4 vb3 = f4[(size_t)rb * 256 + 3 * 64 + lane];
            float accT;
            accT = 0.f; DSQ(va0, c0) DSQ(va1, c1) DSQ(va2, c2) DSQ(va3, c3)
            float accA = accT;
            accT = 0.f; DSQ(vb0, c0) DSQ(vb1, c1) DSQ(vb2, c2) DSQ(vb3, c3)
            float accB = accT;
            for (int o = 32; o >= 1; o >>= 1) {
                accA += __shfl_down(accA, o, 64);
                accB += __shfl_down(accB, o, 64);
            }
            if (lane == 0) wsum += sqrtf(accA) + sqrtf(accB);
        }
        if (i < rend) {
            int ra = ord[i];
            float4 va0 = f4[(size_t)ra * 256 + 0 * 64 + lane];
            float4 va1 = f4[(size_t)ra * 256 + 1 * 64 + lane];
            float4 va2 = f4[(size_t)ra * 256 + 2 * 64 + lane];
            float4 va3 = f4[(size_t)ra * 256 + 3 * 64 + lane];
            float accT = 0.f;
            DSQ(va0, c0) DSQ(va1, c1) DSQ(va2, c2) DSQ(va3, c3)
            for (int o = 32; o >= 1; o >>= 1) accT += __shfl_down(accT, o, 64);
            if (lane == 0) wsum += sqrtf(accT);
        }
        if (lane == 0) red[w] = wsum;
        __syncthreads();
        if (tid == 0) distp[vc] = red[0] + red[1] + red[2] + red[3];
        __syncthreads();
    }
}

__global__ __launch_bounds__(256) void k7_final(float* __restrict__ ws, float* __restrict__ out) {
    __shared__ float red[256];
    __shared__ float winter[4];
    __shared__ int wcnt[4];
    int tid = threadIdx.x, lane = tid & 63, w = tid >> 6;
    const int* cnts = (const int*)ws + F_CNT;
    int c0 = tid & 15, g = tid >> 4;
    const float* dp = ws + F_DISTP;
    float s = 0.f;
    for (int k = g; k < VCPC; k += 16) s += dp[(c0 << 8) + k];
    red[tid] = s;
    __syncthreads();
    const float4* c4 = (const float4*)(ws + F_CENT);
    float interAcc = 0.f; int pairAcc = 0;
    for (int p = w; p < 120; p += 4) {
        int i = 0, rem = p;
        while (rem >= 15 - i) { rem -= 15 - i; ++i; }
        int j = i + 1 + rem;
        int ci = cnts[i], cj = cnts[j];
        float acc = 0.f;
#pragma unroll
        for (int k = 0; k < 4; ++k) {
            float4 a = c4[i * 256 + k * 64 + lane];
            float4 b = c4[j * 256 + k * 64 + lane];
            float dx = a.x - b.x, dy = a.y - b.y, dz = a.z - b.z, dw = a.w - b.w;
            acc += dx * dx + dy * dy + dz * dz + dw * dw;
        }
        for (int o = 32; o >= 1; o >>= 1) acc += __shfl_down(acc, o, 64);
        if (lane == 0 && ci > 0 && cj > 0) {
            float t = MARGINc - sqrtf(acc);
            if (t > 0.f) interAcc += t;
            pairAcc += 1;
        }
    }
    if (lane == 0) { winter[w] = interAcc; wcnt[w] = pairAcc; }
    __syncthreads();
    if (tid == 0) {
        float interSum = winter[0] + winter[1] + winter[2] + winter[3];
        int np = wcnt[0] + wcnt[1] + wcnt[2] + wcnt[3];
        float inter = np > 0 ? interSum / (float)np : 0.f;
        float intra = 0.f; int nv = 0;
        for (int cc = 0; cc < NCLS; ++cc) {
            float dsum = 0.f;
            for (int gg = 0; gg < 16; ++gg) dsum += red[gg * 16 + cc];
            if (cnts[cc] > 0) { intra += dsum * ws[F_INV + cc]; nv++; }
        }
        intra = nv > 0 ? intra / (float)nv : 0.f;
        float ce = ws[F_CE] / (float)B_ROWS;
        out[0] = ce + inter + intra;
    }
}

extern "C" void kernel_launch(void* const* d_in, const int* in_sizes, int n_in,
                              void* d_out, int out_size, void* d_ws, size_t ws_size,
                              hipStream_t stream) {
    const float* logits = (const float*)d_in[0];
    const int* labels   = (const int*)d_in[1];
    const float* feat   = (const float*)d_in[2];
    float* ws  = (float*)d_ws;
    float* out = (float*)d_out;

    // size cooperative grid from the occupancy contract (pure host queries)
    int dev = 0;
    (void)hipGetDevice(&dev);
    int nCU = 0;
    (void)hipDeviceGetAttribute(&nCU, hipDeviceAttributeMultiprocessorCount, dev);
    int maxB = 0;
    (void)hipOccupancyMaxActiveBlocksPerMultiprocessor(&maxB, (const void*)k_mega, 256, 0);
    long nb = (long)maxB * (long)nCU;
    int NB = (int)(nb > NWIN ? NWIN : nb);

    hipError_t err = hipErrorUnknown;
    if (NB >= 1) {
        void* args[] = {(void*)&logits, (void*)&labels, (void*)&feat, (void*)&ws, (void*)&out};
        err = hipLaunchCooperativeKernel((const void*)k_mega, dim3(NB), dim3(256), args, 0, stream);
    }
    if (err != hipSuccess) {
        (void)hipGetLastError();   // clear the non-sticky launch error
        // fallback: proven R7 7-kernel pipeline (147.6 us)
        hipLaunchKernelGGL(k7_ce_hist, dim3(256),       dim3(256),  0, stream, logits, labels, ws);
        hipLaunchKernelGGL(k7_prefix,  dim3(1),         dim3(1024), 0, stream, ws);
        hipLaunchKernelGGL(k7_scatter, dim3(256),       dim3(256),  0, stream, labels, ws);
        hipLaunchKernelGGL(k7_csums,   dim3(NBLK_CS),   dim3(256),  0, stream, feat, ws);
        hipLaunchKernelGGL(k7_cent,    dim3(64),        dim3(256),  0, stream, ws);
        hipLaunchKernelGGL(k7_dist,    dim3(NBLK_DIST), dim3(256),  0, stream, feat, ws);
        hipLaunchKernelGGL(k7_final,   dim3(1),         dim3(256),  0, stream, ws, out);
    }
}

// Round 10
// 181.655 us; speedup vs baseline: 2.7688x; 2.7688x over previous
//
#include <hip/hip_runtime.h>
#include <math.h>

#define NCLS      16
#define B_ROWS    65536
#define MARGINc   1.0f
#define CHUNK     32
#define VCPC      256      // virtual chunks per class (covers cnt <= 8192)
#define KMAXPC    256
#define NBLK_CS   2048
#define NBLK_DIST 2048
#define NWIN      1024     // 64-row windows for hist/scatter

// ws float offsets — every region write-before-read each call
#define W_CNT    32        // 16 int
#define W_OFFS   48        // 16 int
#define W_INV    64        // 16 f32
#define W_CEPART 256       // 1024 f32
#define W_HIST   2048      // 16*1024 int  (hist[c*1024 + win])
#define W_CENT   65536     // 16384 f32
#define W_ORDER  81920     // 65536 int
#define W_DISTP  147456    // 4096 f32
#define W_PART   163840    // 16*256*1024 f32 (16.8 MB)

#define CADD(V) { acc.x += V.x; acc.y += V.y; acc.z += V.z; acc.w += V.w; }
#define DSQ(V, C) { float dx = V.x - C.x, dy = V.y - C.y, dz = V.z - C.z, dw = V.w - C.w; \
                    accT += dx * dx + dy * dy + dz * dz + dw * dw; }

// CE partial + per-window class histogram. 1024 blocks x 64 rows; 4 lanes/row.
__global__ __launch_bounds__(256) void k_ce_hist(const float* __restrict__ logits,
                                                 const int* __restrict__ labels,
                                                 float* __restrict__ ws) {
    __shared__ int ish[NCLS];
    __shared__ float fsh[4];
    int tid = threadIdx.x, lane = tid & 63, w = tid >> 6;
    int vb = blockIdx.x;                       // grid 1024
    int* wsi = (int*)ws;
    if (tid < NCLS) ish[tid] = 0;
    __syncthreads();

    int q = tid >> 2, sub = tid & 3;
    int row = vb * 64 + q;
    float4 lg = ((const float4*)(logits + (size_t)row * 16))[sub];
    int lab = labels[row];
    float m = fmaxf(fmaxf(lg.x, lg.y), fmaxf(lg.z, lg.w));
    m = fmaxf(m, __shfl_xor(m, 1, 64));
    m = fmaxf(m, __shfl_xor(m, 2, 64));
    float s = expf(lg.x - m) + expf(lg.y - m) + expf(lg.z - m) + expf(lg.w - m);
    s += __shfl_xor(s, 1, 64);
    s += __shfl_xor(s, 2, 64);
    float pick = 0.f;
    if ((lab >> 2) == sub) {
        int cmp = lab & 3;
        pick = cmp == 0 ? lg.x : cmp == 1 ? lg.y : cmp == 2 ? lg.z : lg.w;
    }
    pick += __shfl_xor(pick, 1, 64);
    pick += __shfl_xor(pick, 2, 64);
    float ce = 0.f;
    if (sub == 0) {
        ce = m + logf(s) - pick;
        atomicAdd(&ish[lab], 1);               // LDS atomic, intra-block
    }
    for (int o = 32; o >= 1; o >>= 1) ce += __shfl_down(ce, o, 64);
    if (lane == 0) fsh[w] = ce;
    __syncthreads();
    if (tid == 0) ws[W_CEPART + vb] = fsh[0] + fsh[1] + fsh[2] + fsh[3];
    if (tid < NCLS) wsi[W_HIST + tid * 1024 + vb] = ish[tid];
}

// Scatter with INLINE prefix: each block wave-scans the (L2-hot) histogram to
// derive its own per-class cursor bases. 1024 blocks x 64 threads (1 wave).
__global__ __launch_bounds__(64) void k_scatter(const int* __restrict__ labels,
                                                float* __restrict__ ws) {
    __shared__ int cur[NCLS];
    int lane = threadIdx.x;
    int b = blockIdx.x;                        // grid 1024
    int* wsi = (int*)ws;
    const int* hist = wsi + W_HIST;

    int offacc = 0;                            // running class offset
#pragma unroll
    for (int c = 0; c < NCLS; ++c) {
        int plt = 0, pall = 0;
        for (int j = lane; j < 1024; j += 64) {
            int h = hist[c * 1024 + j];
            pall += h;
            if (j < b) plt += h;
        }
        for (int o = 32; o >= 1; o >>= 1) {
            plt  += __shfl_down(plt, o, 64);
            pall += __shfl_down(pall, o, 64);
        }
        int cum = __shfl(plt, 0, 64);
        int tot = __shfl(pall, 0, 64);
        if (lane == 0) {
            cur[c] = offacc + cum;
            if (b == 0) {
                wsi[W_CNT + c] = tot;
                wsi[W_OFFS + c] = offacc;
                ws[W_INV + c] = 1.0f / (float)(tot > 0 ? tot : 1);
            }
        }
        offacc += tot;
    }
    __syncthreads();
    int row = b * 64 + lane;
    int lab = labels[row];
    int pos = atomicAdd(&cur[lab], 1);         // LDS atomic
    wsi[W_ORDER + pos] = row;
}

// class sums over sorted order (forward chunk order), register accumulate,
// flush = plain float4 store per (class,chunk)
__global__ __launch_bounds__(256) void k_csums(const float* __restrict__ feat,
                                               float* __restrict__ ws) {
    int tid = threadIdx.x;
    const int* cnts  = (const int*)ws + W_CNT;
    const int* offs  = (const int*)ws + W_OFFS;
    const int* order = (const int*)ws + W_ORDER;
    const float4* f4 = (const float4*)feat;
    float4* part4 = (float4*)(ws + W_PART);

    for (int vc = blockIdx.x; vc < NCLS * VCPC; vc += NBLK_CS) {
        int c = vc >> 8, k = vc & (VCPC - 1);
        int cnt = cnts[c];
        int s0 = k * CHUNK;
        if (s0 >= cnt) continue;
        int e = s0 + CHUNK; if (e > cnt) e = cnt;
        const int* ord = order + offs[c] + s0;
        int n = e - s0;
        float4 acc = make_float4(0.f, 0.f, 0.f, 0.f);
        int i = 0;
        for (; i + 8 <= n; i += 8) {
            int i0 = ord[i], i1 = ord[i + 1], i2 = ord[i + 2], i3 = ord[i + 3];
            int i4 = ord[i + 4], i5 = ord[i + 5], i6 = ord[i + 6], i7 = ord[i + 7];
            float4 v0 = f4[(size_t)i0 * 256 + tid];
            float4 v1 = f4[(size_t)i1 * 256 + tid];
            float4 v2 = f4[(size_t)i2 * 256 + tid];
            float4 v3 = f4[(size_t)i3 * 256 + tid];
            float4 v4 = f4[(size_t)i4 * 256 + tid];
            float4 v5 = f4[(size_t)i5 * 256 + tid];
            float4 v6 = f4[(size_t)i6 * 256 + tid];
            float4 v7 = f4[(size_t)i7 * 256 + tid];
            CADD(v0) CADD(v1) CADD(v2) CADD(v3)
            CADD(v4) CADD(v5) CADD(v6) CADD(v7)
        }
        for (; i < n; ++i) {
            float4 v = f4[(size_t)ord[i] * 256 + tid];
            CADD(v)
        }
        part4[(size_t)vc * 256 + tid] = acc;   // plain store
    }
}

// bounded partial reduce -> centroids (x inv count)
__global__ __launch_bounds__(256) void k_cent(float* __restrict__ ws) {
    int j = blockIdx.x * 256 + threadIdx.x;    // grid 64 -> 16384
    int c = j >> 10, d = j & 1023;
    int cnt = ((const int*)ws)[W_CNT + c];
    int kmax = (cnt + CHUNK - 1) >> 5;
    const float* part = ws + W_PART + (size_t)c * KMAXPC * 1024 + d;
    float s = 0.f;
    int k = 0;
    for (; k + 4 <= kmax; k += 4)
        s += part[(size_t)k * 1024] + part[(size_t)(k + 1) * 1024]
           + part[(size_t)(k + 2) * 1024] + part[(size_t)(k + 3) * 1024];
    for (; k < kmax; ++k) s += part[(size_t)k * 1024];
    ws[W_CENT + j] = s * ws[W_INV + c];
}

// distances over the SAME chunk sequence as csums but REVERSED (L3 reuse);
// class is chunk-uniform -> centroid in 4 registers/lane
__global__ __launch_bounds__(256) void k_dist(const float* __restrict__ feat,
                                              float* __restrict__ ws) {
    __shared__ float red[4];
    int tid = threadIdx.x, lane = tid & 63, w = tid >> 6;
    const int* cnts  = (const int*)ws + W_CNT;
    const int* offs  = (const int*)ws + W_OFFS;
    const int* order = (const int*)ws + W_ORDER;
    const float4* f4 = (const float4*)feat;
    const float4* c4 = (const float4*)(ws + W_CENT);
    float* distp = ws + W_DISTP;

    for (int it = 0; it < (NCLS * VCPC) / NBLK_DIST; ++it) {
        int vc = (NCLS * VCPC - 1) - (blockIdx.x + it * NBLK_DIST);   // reverse
        int c = vc >> 8, k = vc & (VCPC - 1);
        int cnt = cnts[c];
        int s0 = k * CHUNK;
        if (s0 >= cnt) { if (tid == 0) distp[vc] = 0.f; continue; }
        int n = cnt - s0; if (n > CHUNK) n = CHUNK;
        const int* ord = order + offs[c] + s0;
        float4 c0 = c4[c * 256 + 0 * 64 + lane];
        float4 c1 = c4[c * 256 + 1 * 64 + lane];
        float4 c2 = c4[c * 256 + 2 * 64 + lane];
        float4 c3 = c4[c * 256 + 3 * 64 + lane];
        float wsum = 0.f;
        int rbeg = w * 8;
        int rend = rbeg + 8; if (rend > n) rend = n;
        int i = rbeg;
        for (; i + 2 <= rend; i += 2) {
            int ra = ord[i], rb = ord[i + 1];
            float4 va0 = f4[(size_t)ra * 256 + 0 * 64 + lane];
            float4 va1 = f4[(size_t)ra * 256 + 1 * 64 + lane];
            float4 va2 = f4[(size_t)ra * 256 + 2 * 64 + lane];
            float4 va3 = f4[(size_t)ra * 256 + 3 * 64 + lane];
            float4 vb0 = f4[(size_t)rb * 256 + 0 * 64 + lane];
            float4 vb1 = f4[(size_t)rb * 256 + 1 * 64 + lane];
            float4 vb2 = f4[(size_t)rb * 256 + 2 * 64 + lane];
            float4 vb3 = f4[(size_t)rb * 256 + 3 * 64 + lane];
            float accT;
            accT = 0.f; DSQ(va0, c0) DSQ(va1, c1) DSQ(va2, c2) DSQ(va3, c3)
            float accA = accT;
            accT = 0.f; DSQ(vb0, c0) DSQ(vb1, c1) DSQ(vb2, c2) DSQ(vb3, c3)
            float accB = accT;
            for (int o = 32; o >= 1; o >>= 1) {
                accA += __shfl_down(accA, o, 64);
                accB += __shfl_down(accB, o, 64);
            }
            if (lane == 0) wsum += sqrtf(accA) + sqrtf(accB);
        }
        if (i < rend) {
            int ra = ord[i];
            float4 va0 = f4[(size_t)ra * 256 + 0 * 64 + lane];
            float4 va1 = f4[(size_t)ra * 256 + 1 * 64 + lane];
            float4 va2 = f4[(size_t)ra * 256 + 2 * 64 + lane];
            float4 va3 = f4[(size_t)ra * 256 + 3 * 64 + lane];
            float accT = 0.f;
            DSQ(va0, c0) DSQ(va1, c1) DSQ(va2, c2) DSQ(va3, c3)
            for (int o = 32; o >= 1; o >>= 1) accT += __shfl_down(accT, o, 64);
            if (lane == 0) wsum += sqrtf(accT);
        }
        if (lane == 0) red[w] = wsum;
        __syncthreads();
        if (tid == 0) distp[vc] = red[0] + red[1] + red[2] + red[3];
        __syncthreads();
    }
}

// single block: CE reduce + dist-chunk reduce + inter-class pairs + combine
__global__ __launch_bounds__(256) void k_final(float* __restrict__ ws, float* __restrict__ out) {
    __shared__ float red[256];
    __shared__ float winter[4];
    __shared__ int wcnt[4];
    __shared__ float cew[4];
    int tid = threadIdx.x, lane = tid & 63, w = tid >> 6;
    const int* cnts = (const int*)ws + W_CNT;

    // CE total from 1024 partials
    float cv = ws[W_CEPART + tid] + ws[W_CEPART + tid + 256]
             + ws[W_CEPART + tid + 512] + ws[W_CEPART + tid + 768];
    for (int o = 32; o >= 1; o >>= 1) cv += __shfl_down(cv, o, 64);
    if (lane == 0) cew[w] = cv;

    // distp reduce: thread (g,c) sums chunks k = g, g+16, ...
    int c0 = tid & 15, g = tid >> 4;
    const float* dp = ws + W_DISTP;
    float s = 0.f;
    for (int k = g; k < VCPC; k += 16) s += dp[(c0 << 8) + k];
    red[tid] = s;
    __syncthreads();

    const float4* c4 = (const float4*)(ws + W_CENT);
    float interAcc = 0.f; int pairAcc = 0;
    for (int p = w; p < 120; p += 4) {
        int i = 0, rem = p;
        while (rem >= 15 - i) { rem -= 15 - i; ++i; }
        int j = i + 1 + rem;
        int ci = cnts[i], cj = cnts[j];
        float acc = 0.f;
#pragma unroll
        for (int k = 0; k < 4; ++k) {
            float4 a = c4[i * 256 + k * 64 + lane];
            float4 b = c4[j * 256 + k * 64 + lane];
            float dx = a.x - b.x, dy = a.y - b.y, dz = a.z - b.z, dw = a.w - b.w;
            acc += dx * dx + dy * dy + dz * dz + dw * dw;
        }
        for (int o = 32; o >= 1; o >>= 1) acc += __shfl_down(acc, o, 64);
        if (lane == 0 && ci > 0 && cj > 0) {
            float t = MARGINc - sqrtf(acc);
            if (t > 0.f) interAcc += t;
            pairAcc += 1;
        }
    }
    if (lane == 0) { winter[w] = interAcc; wcnt[w] = pairAcc; }
    __syncthreads();
    if (tid == 0) {
        float interSum = winter[0] + winter[1] + winter[2] + winter[3];
        int np = wcnt[0] + wcnt[1] + wcnt[2] + wcnt[3];
        float inter = np > 0 ? interSum / (float)np : 0.f;
        float intra = 0.f; int nv = 0;
        for (int cc = 0; cc < NCLS; ++cc) {
            float dsum = 0.f;
            for (int gg = 0; gg < 16; ++gg) dsum += red[gg * 16 + cc];
            if (cnts[cc] > 0) { intra += dsum * ws[W_INV + cc]; nv++; }
        }
        intra = nv > 0 ? intra / (float)nv : 0.f;
        float ce = (cew[0] + cew[1] + cew[2] + cew[3]) / (float)B_ROWS;
        out[0] = ce + inter + intra;
    }
}

extern "C" void kernel_launch(void* const* d_in, const int* in_sizes, int n_in,
                              void* d_out, int out_size, void* d_ws, size_t ws_size,
                              hipStream_t stream) {
    const float* logits = (const float*)d_in[0];
    const int* labels   = (const int*)d_in[1];
    const float* feat   = (const float*)d_in[2];
    float* ws  = (float*)d_ws;
    float* out = (float*)d_out;

    hipLaunchKernelGGL(k_ce_hist, dim3(NWIN),      dim3(256), 0, stream, logits, labels, ws);
    hipLaunchKernelGGL(k_scatter, dim3(NWIN),      dim3(64),  0, stream, labels, ws);
    hipLaunchKernelGGL(k_csums,   dim3(NBLK_CS),   dim3(256), 0, stream, feat, ws);
    hipLaunchKernelGGL(k_cent,    dim3(64),        dim3(256), 0, stream, ws);
    hipLaunchKernelGGL(k_dist,    dim3(NBLK_DIST), dim3(256), 0, stream, feat, ws);
    hipLaunchKernelGGL(k_final,   dim3(1),         dim3(256), 0, stream, ws, out);
}

// Round 11
// 139.978 us; speedup vs baseline: 3.5931x; 1.2977x over previous
//
#include <hip/hip_runtime.h>
#include <math.h>

#define NCLS      16
#define B_ROWS    65536
#define MARGINc   1.0f
#define CHUNK     64
#define CPC       128      // chunks per class (covers cnt <= 8192)
#define NCHUNK    (NCLS * CPC)   // 2048

// ws float offsets — every region write-before-read each call
#define F_CE     0
#define F_CNT    32        // 16 int
#define F_OFFS   48        // 16 int
#define F_INV    64        // 16 f32
#define F_CEPART 256       // 256 f32
#define F_HIST   1024      // 16*256 int  (hist[c*256 + b])
#define F_BASES  8192      // 16*256 int
#define F_CENT   16384     // 16384 f32
#define F_ORDER  32768     // 65536 int
#define F_DISTP  98304     // 2048 f32
#define F_PART   131072    // 16*128*1024 f32 (8.4 MB)

#define CADD(V) { acc.x += V.x; acc.y += V.y; acc.z += V.z; acc.w += V.w; }
#define DSQ(V, C) { float dx = V.x - C.x, dy = V.y - C.y, dz = V.z - C.z, dw = V.w - C.w; \
                    accT += dx * dx + dy * dy + dz * dz + dw * dw; }

// CE + per-block class histogram (R7-proven). 256 blocks x 256 rows.
__global__ __launch_bounds__(256) void k_ce_hist(const float* __restrict__ logits,
                                                 const int* __restrict__ labels,
                                                 float* __restrict__ ws) {
    __shared__ int hist[NCLS];
    __shared__ float cew[4];
    int tid = threadIdx.x, lane = tid & 63, w = tid >> 6;
    int b = blockIdx.x;
    if (tid < NCLS) hist[tid] = 0;
    __syncthreads();
    int row = b * 256 + tid;
    const float4* lg = (const float4*)(logits + (size_t)row * 16);
    float4 a = lg[0], b4 = lg[1], c = lg[2], d = lg[3];
    float m = fmaxf(fmaxf(fmaxf(a.x, a.y), fmaxf(a.z, a.w)),
                    fmaxf(fmaxf(b4.x, b4.y), fmaxf(b4.z, b4.w)));
    m = fmaxf(m, fmaxf(fmaxf(c.x, c.y), fmaxf(c.z, c.w)));
    m = fmaxf(m, fmaxf(fmaxf(d.x, d.y), fmaxf(d.z, d.w)));
    float s = expf(a.x - m) + expf(a.y - m) + expf(a.z - m) + expf(a.w - m)
            + expf(b4.x - m) + expf(b4.y - m) + expf(b4.z - m) + expf(b4.w - m)
            + expf(c.x - m) + expf(c.y - m) + expf(c.z - m) + expf(c.w - m)
            + expf(d.x - m) + expf(d.y - m) + expf(d.z - m) + expf(d.w - m);
    int lab = labels[row];
    atomicAdd(&hist[lab], 1);
    float xl = logits[(size_t)row * 16 + lab];
    float ce = (m + logf(s)) - xl;
    for (int o = 32; o >= 1; o >>= 1) ce += __shfl_down(ce, o, 64);
    if (lane == 0) cew[w] = ce;
    __syncthreads();
    if (tid == 0) ws[F_CEPART + b] = cew[0] + cew[1] + cew[2] + cew[3];
    if (tid < NCLS) ((int*)ws)[F_HIST + tid * 256 + b] = hist[tid];
}

// One 1024-thread block (wave = class): scan per-block counts -> bases, etc.
__global__ __launch_bounds__(1024) void k_prefix(float* __restrict__ ws) {
    __shared__ int ctot[NCLS];
    __shared__ float cew[4];
    int tid = threadIdx.x, lane = tid & 63, w = tid >> 6;
    const int* hist = (const int*)ws + F_HIST;
    int* bases = (int*)ws + F_BASES;
    int base = lane * 4;
    int v0 = hist[w * 256 + base + 0];
    int v1 = hist[w * 256 + base + 1];
    int v2 = hist[w * 256 + base + 2];
    int v3 = hist[w * 256 + base + 3];
    int tot = v0 + v1 + v2 + v3;
    int x = tot;
    for (int o = 1; o < 64; o <<= 1) {
        int y = __shfl_up(x, o, 64);
        if (lane >= o) x += y;
    }
    int excl = x - tot;
    if (lane == 63) ctot[w] = x;
    __syncthreads();
    int off = 0;
    for (int cc = 0; cc < NCLS; ++cc) if (cc < w) off += ctot[cc];
    bases[w * 256 + base + 0] = off + excl;
    bases[w * 256 + base + 1] = off + excl + v0;
    bases[w * 256 + base + 2] = off + excl + v0 + v1;
    bases[w * 256 + base + 3] = off + excl + v0 + v1 + v2;
    if (lane == 0) {
        int cnt = ctot[w];
        ((int*)ws)[F_CNT + w] = cnt;
        ((int*)ws)[F_OFFS + w] = off;
        ws[F_INV + w] = 1.0f / (float)(cnt > 0 ? cnt : 1);
    }
    float s = (tid < 256) ? ws[F_CEPART + tid] : 0.f;
    if (tid < 256) {
        for (int o = 32; o >= 1; o >>= 1) s += __shfl_down(s, o, 64);
        if (lane == 0) cew[w] = s;
    }
    __syncthreads();
    if (tid == 0) ws[F_CE] = cew[0] + cew[1] + cew[2] + cew[3];
}

// counting-sort scatter (LDS cursors from bases)
__global__ __launch_bounds__(256) void k_scatter(const int* __restrict__ labels,
                                                 float* __restrict__ ws) {
    __shared__ int cur[NCLS];
    int tid = threadIdx.x, b = blockIdx.x;
    if (tid < NCLS) cur[tid] = ((int*)ws)[F_BASES + tid * 256 + b];
    __syncthreads();
    int row = b * 256 + tid;
    int lab = labels[row];
    int pos = atomicAdd(&cur[lab], 1);
    ((int*)ws)[F_ORDER + pos] = row;
}

// class sums: ONE block per 64-row chunk (grid 2048), register accumulate,
// flush = plain float4 store
__global__ __launch_bounds__(256) void k_csums(const float* __restrict__ feat,
                                               float* __restrict__ ws) {
    int tid = threadIdx.x;
    int vc = blockIdx.x;                       // grid NCHUNK
    int c = vc >> 7, k = vc & (CPC - 1);
    const int* cnts  = (const int*)ws + F_CNT;
    const int* offs  = (const int*)ws + F_OFFS;
    const int* order = (const int*)ws + F_ORDER;
    const float4* f4 = (const float4*)feat;
    float4* part4 = (float4*)(ws + F_PART);

    int cnt = cnts[c];
    int s0 = k * CHUNK;
    float4 acc = make_float4(0.f, 0.f, 0.f, 0.f);
    if (s0 < cnt) {
        int e = s0 + CHUNK; if (e > cnt) e = cnt;
        const int* ord = order + offs[c] + s0;
        int n = e - s0;
        int i = 0;
        for (; i + 8 <= n; i += 8) {
            int i0 = ord[i], i1 = ord[i + 1], i2 = ord[i + 2], i3 = ord[i + 3];
            int i4 = ord[i + 4], i5 = ord[i + 5], i6 = ord[i + 6], i7 = ord[i + 7];
            float4 v0 = f4[(size_t)i0 * 256 + tid];
            float4 v1 = f4[(size_t)i1 * 256 + tid];
            float4 v2 = f4[(size_t)i2 * 256 + tid];
            float4 v3 = f4[(size_t)i3 * 256 + tid];
            float4 v4 = f4[(size_t)i4 * 256 + tid];
            float4 v5 = f4[(size_t)i5 * 256 + tid];
            float4 v6 = f4[(size_t)i6 * 256 + tid];
            float4 v7 = f4[(size_t)i7 * 256 + tid];
            CADD(v0) CADD(v1) CADD(v2) CADD(v3)
            CADD(v4) CADD(v5) CADD(v6) CADD(v7)
        }
        for (; i < n; ++i) {
            float4 v = f4[(size_t)ord[i] * 256 + tid];
            CADD(v)
        }
    }
    part4[(size_t)vc * 256 + tid] = acc;       // store zeros for empty chunks too
}

// partial reduce -> centroids (x inv count); partials are zero-padded
__global__ __launch_bounds__(256) void k_cent(float* __restrict__ ws) {
    int j = blockIdx.x * 256 + threadIdx.x;    // grid 64 -> 16384
    int c = j >> 10, d = j & 1023;
    int cnt = ((const int*)ws)[F_CNT + c];
    int kmax = (cnt + CHUNK - 1) >> 6;
    const float* part = ws + F_PART + (size_t)c * CPC * 1024 + d;
    float s = 0.f;
    int k = 0;
    for (; k + 4 <= kmax; k += 4)
        s += part[(size_t)k * 1024] + part[(size_t)(k + 1) * 1024]
           + part[(size_t)(k + 2) * 1024] + part[(size_t)(k + 3) * 1024];
    for (; k < kmax; ++k) s += part[(size_t)k * 1024];
    ws[F_CENT + j] = s * ws[F_INV + c];
}

// distances: ONE block per chunk, REVERSE of csums order (L3 stack reuse);
// class is chunk-uniform -> centroid in 4 registers/lane
__global__ __launch_bounds__(256) void k_dist(const float* __restrict__ feat,
                                              float* __restrict__ ws) {
    __shared__ float red[4];
    int tid = threadIdx.x, lane = tid & 63, w = tid >> 6;
    int vc = (NCHUNK - 1) - blockIdx.x;        // reverse mapping
    int c = vc >> 7, k = vc & (CPC - 1);
    const int* cnts  = (const int*)ws + F_CNT;
    const int* offs  = (const int*)ws + F_OFFS;
    const int* order = (const int*)ws + F_ORDER;
    const float4* f4 = (const float4*)feat;
    const float4* c4 = (const float4*)(ws + F_CENT);
    float* distp = ws + F_DISTP;

    int cnt = cnts[c];
    int s0 = k * CHUNK;
    if (s0 >= cnt) { if (tid == 0) distp[vc] = 0.f; return; }
    int n = cnt - s0; if (n > CHUNK) n = CHUNK;
    const int* ord = order + offs[c] + s0;

    float4 c0 = c4[c * 256 + 0 * 64 + lane];
    float4 c1 = c4[c * 256 + 1 * 64 + lane];
    float4 c2 = c4[c * 256 + 2 * 64 + lane];
    float4 c3 = c4[c * 256 + 3 * 64 + lane];

    float wsum = 0.f;
    int rbeg = w * 16;
    int rend = rbeg + 16; if (rend > n) rend = n;
    int i = rbeg;
    for (; i + 2 <= rend; i += 2) {
        int ra = ord[i], rb = ord[i + 1];
        float4 va0 = f4[(size_t)ra * 256 + 0 * 64 + lane];
        float4 va1 = f4[(size_t)ra * 256 + 1 * 64 + lane];
        float4 va2 = f4[(size_t)ra * 256 + 2 * 64 + lane];
        float4 va3 = f4[(size_t)ra * 256 + 3 * 64 + lane];
        float4 vb0 = f4[(size_t)rb * 256 + 0 * 64 + lane];
        float4 vb1 = f4[(size_t)rb * 256 + 1 * 64 + lane];
        float4 vb2 = f4[(size_t)rb * 256 + 2 * 64 + lane];
        float4 vb3 = f4[(size_t)rb * 256 + 3 * 64 + lane];
        float accT;
        accT = 0.f; DSQ(va0, c0) DSQ(va1, c1) DSQ(va2, c2) DSQ(va3, c3)
        float accA = accT;
        accT = 0.f; DSQ(vb0, c0) DSQ(vb1, c1) DSQ(vb2, c2) DSQ(vb3, c3)
        float accB = accT;
        for (int o = 32; o >= 1; o >>= 1) {
            accA += __shfl_down(accA, o, 64);
            accB += __shfl_down(accB, o, 64);
        }
        if (lane == 0) wsum += sqrtf(accA) + sqrtf(accB);
    }
    if (i < rend) {
        int ra = ord[i];
        float4 va0 = f4[(size_t)ra * 256 + 0 * 64 + lane];
        float4 va1 = f4[(size_t)ra * 256 + 1 * 64 + lane];
        float4 va2 = f4[(size_t)ra * 256 + 2 * 64 + lane];
        float4 va3 = f4[(size_t)ra * 256 + 3 * 64 + lane];
        float accT = 0.f;
        DSQ(va0, c0) DSQ(va1, c1) DSQ(va2, c2) DSQ(va3, c3)
        for (int o = 32; o >= 1; o >>= 1) accT += __shfl_down(accT, o, 64);
        if (lane == 0) wsum += sqrtf(accT);
    }
    if (lane == 0) red[w] = wsum;
    __syncthreads();
    if (tid == 0) distp[vc] = red[0] + red[1] + red[2] + red[3];
}

// single block: dist-chunk reduce + inter-class pairs + combine
__global__ __launch_bounds__(256) void k_final(float* __restrict__ ws, float* __restrict__ out) {
    __shared__ float red[256];
    __shared__ float winter[4];
    __shared__ int wcnt[4];
    int tid = threadIdx.x, lane = tid & 63, w = tid >> 6;
    const int* cnts = (const int*)ws + F_CNT;

    // distp reduce: thread (g,c) sums chunks k = g, g+16, ... (CPC=128)
    int c0 = tid & 15, g = tid >> 4;
    const float* dp = ws + F_DISTP;
    float s = 0.f;
    for (int k = g; k < CPC; k += 16) s += dp[(c0 << 7) + k];
    red[tid] = s;
    __syncthreads();

    const float4* c4 = (const float4*)(ws + F_CENT);
    float interAcc = 0.f; int pairAcc = 0;
    for (int p = w; p < 120; p += 4) {
        int i = 0, rem = p;
        while (rem >= 15 - i) { rem -= 15 - i; ++i; }
        int j = i + 1 + rem;
        int ci = cnts[i], cj = cnts[j];
        float acc = 0.f;
#pragma unroll
        for (int k = 0; k < 4; ++k) {
            float4 a = c4[i * 256 + k * 64 + lane];
            float4 b = c4[j * 256 + k * 64 + lane];
            float dx = a.x - b.x, dy = a.y - b.y, dz = a.z - b.z, dw = a.w - b.w;
            acc += dx * dx + dy * dy + dz * dz + dw * dw;
        }
        for (int o = 32; o >= 1; o >>= 1) acc += __shfl_down(acc, o, 64);
        if (lane == 0 && ci > 0 && cj > 0) {
            float t = MARGINc - sqrtf(acc);
            if (t > 0.f) interAcc += t;
            pairAcc += 1;
        }
    }
    if (lane == 0) { winter[w] = interAcc; wcnt[w] = pairAcc; }
    __syncthreads();
    if (tid == 0) {
        float interSum = winter[0] + winter[1] + winter[2] + winter[3];
        int np = wcnt[0] + wcnt[1] + wcnt[2] + wcnt[3];
        float inter = np > 0 ? interSum / (float)np : 0.f;
        float intra = 0.f; int nv = 0;
        for (int cc = 0; cc < NCLS; ++cc) {
            float dsum = 0.f;
            for (int gg = 0; gg < 16; ++gg) dsum += red[gg * 16 + cc];
            if (cnts[cc] > 0) { intra += dsum * ws[F_INV + cc]; nv++; }
        }
        intra = nv > 0 ? intra / (float)nv : 0.f;
        float ce = ws[F_CE] / (float)B_ROWS;
        out[0] = ce + inter + intra;
    }
}

extern "C" void kernel_launch(void* const* d_in, const int* in_sizes, int n_in,
                              void* d_out, int out_size, void* d_ws, size_t ws_size,
                              hipStream_t stream) {
    const float* logits = (const float*)d_in[0];
    const int* labels   = (const int*)d_in[1];
    const float* feat   = (const float*)d_in[2];
    float* ws  = (float*)d_ws;
    float* out = (float*)d_out;

    hipLaunchKernelGGL(k_ce_hist, dim3(256),    dim3(256),  0, stream, logits, labels, ws);
    hipLaunchKernelGGL(k_prefix,  dim3(1),      dim3(1024), 0, stream, ws);
    hipLaunchKernelGGL(k_scatter, dim3(256),    dim3(256),  0, stream, labels, ws);
    hipLaunchKernelGGL(k_csums,   dim3(NCHUNK), dim3(256),  0, stream, feat, ws);
    hipLaunchKernelGGL(k_cent,    dim3(64),     dim3(256),  0, stream, ws);
    hipLaunchKernelGGL(k_dist,    dim3(NCHUNK), dim3(256),  0, stream, feat, ws);
    hipLaunchKernelGGL(k_final,   dim3(1),      dim3(256),  0, stream, ws, out);
}